// Round 9
// baseline (71.814 us; speedup 1.0000x reference)
//
#include <hip/hip_runtime.h>
#include <stdint.h>

typedef __attribute__((ext_vector_type(8))) short bf16x8;
typedef __attribute__((ext_vector_type(4))) float f32x4;
typedef unsigned short ushort_t;

#define NE 6291456   // 8*1024*12*64 elements

__device__ __forceinline__ unsigned short f2bf(float f){
  union { float f; unsigned u; } c; c.f = f;
  unsigned u = c.u;
  u = u + 0x7FFFu + ((u >> 16) & 1u);
  return (unsigned short)(u >> 16);
}

__device__ __forceinline__ bf16x8 cvt8(const float* p){
  const float4 a = ((const float4*)p)[0];
  const float4 b = ((const float4*)p)[1];
  bf16x8 r;
  r[0]=(short)f2bf(a.x); r[1]=(short)f2bf(a.y); r[2]=(short)f2bf(a.z); r[3]=(short)f2bf(a.w);
  r[4]=(short)f2bf(b.x); r[5]=(short)f2bf(b.y); r[6]=(short)f2bf(b.z); r[7]=(short)f2bf(b.w);
  return r;
}

__device__ __forceinline__ uint32_t pk2bf(float a, float b){
  uint32_t r;
  asm("v_cvt_pk_bf16_f32 %0, %1, %2" : "=v"(r) : "v"(a), "v"(b));
  return r;
}

__device__ __forceinline__ float exp2x(float x){
  float r;
  asm("v_exp_f32 %0, %1" : "=v"(r) : "v"(x));
  return r;
}

__device__ __forceinline__ void gll16(const ushort_t* g, short* l){
  __builtin_amdgcn_global_load_lds(
      (const __attribute__((address_space(1))) unsigned int*)g,
      (__attribute__((address_space(3))) unsigned int*)l, 16, 0, 0);
}

// rr (0..11) -> key index, dx, d
__device__ __forceinline__ void rr_decode(int rr, int& i, int& dx, int& d){
  if (rr < 2){ i = rr; dx = 0; d = 1; }
  else { i = 2 + ((rr-2)>>1); dx = (rr-2)&1; d = 2; }
}

// ---------------- Kernel 0: weight pre-convert f32 -> bf16 ----------------
__global__ __launch_bounds__(256) void wconv(
    const float* __restrict__ Wq, const float* __restrict__ Wk,
    const float* __restrict__ Wv, const float* __restrict__ Wo,
    ushort_t* __restrict__ out)
{
  const int a = blockIdx.y;
  const float* src = (a==0)?Wq:(a==1)?Wk:(a==2)?Wv:Wo;
  const float sc = (a==0) ? 0.14724743479535623f : 1.0f;  // log2(e)/sqrt(96)
  const int i = (blockIdx.x*256 + threadIdx.x)*8;
  float4 v0 = *(const float4*)(src+i);
  float4 v1 = *(const float4*)(src+i+4);
  uint4 o;
  o.x = pk2bf(v0.x*sc, v0.y*sc);
  o.y = pk2bf(v0.z*sc, v0.w*sc);
  o.z = pk2bf(v1.x*sc, v1.y*sc);
  o.w = pk2bf(v1.z*sc, v1.w*sc);
  *(uint4*)(out + (size_t)a*28672 + i) = o;
}

// ---------------- Kernel A: QKV projection ----------------
// Block = (rr, 64 bs-rows). Q: register-direct C^T stores to Qg (64-s tiles).
// K,V: combined KVg buffer, 32-kv groups of 6144 shorts: [K 3072][V 3072].
__global__ __launch_bounds__(256) void qkv_proj(
    const float* __restrict__ xA1, const float* __restrict__ xB2,
    const float* __restrict__ xE1, const float* __restrict__ xE2,
    const float* __restrict__ xE3, const float* __restrict__ xE4,
    const float* __restrict__ xE5,
    const ushort_t* __restrict__ Wb4,
    ushort_t* __restrict__ Qg, ushort_t* __restrict__ KVg)
{
  __shared__ short Cl[64*72];            // V out tile [64 s][64 o], stride 72

  const int tile = blockIdx.x;           // 0..1535
  const int rr = tile >> 7, rt = tile & 127;
  int i, dx, d; rr_decode(rr, i, dx, d);
  const float* xp = (i==0)?xA1:(i==1)?xB2:(i==2)?xE1:(i==3)?xE2:(i==4)?xE3:(i==5)?xE4:xE5;

  const int lane = threadIdx.x & 63;
  const int w    = threadIdx.x >> 6;
  const int lo = lane & 15, hi = lane >> 4;
  const int b8 = (rt >> 4) * 8;
  const int tile64 = rt & 15;

  bf16x8 afr[2];
  {
    const int R = rt*64 + w*16 + lo;
    const float* rp = xp + (size_t)(R*d + dx) * 64;
    afr[0] = cvt8(rp + 8*hi);
    afr[1] = cvt8(rp + 32 + 8*hi);
  }

  // ---- Q: C^T form, register-direct stores (64-s tile layout) ----
  {
    const ushort_t* Wb = Wb4 + (size_t)i * 4096;
    #pragma unroll
    for (int ot = 0; ot < 4; ++ot){
      f32x4 acc = {0.f,0.f,0.f,0.f};
      #pragma unroll
      for (int c = 0; c < 2; ++c){
        bf16x8 bfr = *(const bf16x8*)(Wb + (size_t)(lo + 16*ot) * 64 + 32*c + 8*hi);
        acc = __builtin_amdgcn_mfma_f32_16x16x32_bf16(bfr, afr[c], acc, 0, 0, 0);
      }
      uint2 o2;
      o2.x = pk2bf(acc[0], acc[1]);
      o2.y = pk2bf(acc[2], acc[3]);
      int hh = 2*ot + (hi>>1);
      size_t a = (size_t)((b8 + hh)*16 + tile64)*6144
               + (size_t)((w*3 + (rr>>2))*64 + (rr&3)*16 + lo)*8 + 4*(hi&1);
      *(uint2*)(Qg + a) = o2;
    }
  }

  // ---- K: C^T form, register-direct stores (32-kv combined layout) ----
  {
    const ushort_t* Wb = Wb4 + (size_t)28672 + (size_t)i * 4096;
    #pragma unroll
    for (int ot = 0; ot < 4; ++ot){
      f32x4 acc = {0.f,0.f,0.f,0.f};
      #pragma unroll
      for (int c = 0; c < 2; ++c){
        bf16x8 bfr = *(const bf16x8*)(Wb + (size_t)(lo + 16*ot) * 64 + 32*c + 8*hi);
        acc = __builtin_amdgcn_mfma_f32_16x16x32_bf16(bfr, afr[c], acc, 0, 0, 0);
      }
      uint2 o2;
      o2.x = pk2bf(acc[0], acc[1]);
      o2.y = pk2bf(acc[2], acc[3]);
      int hh = 2*ot + (hi>>1);
      size_t a = (size_t)((b8 + hh)*32 + tile64*2 + (w>>1))*6144
               + (size_t)(((w&1)*3 + (rr>>2))*64 + (rr&3)*16 + lo)*8 + 4*(hi&1);
      *(uint2*)(KVg + a) = o2;
    }
  }

  // ---- V: via LDS permute path (pi-permuted kv slots) ----
  {
    const ushort_t* Wb = Wb4 + (size_t)2*28672 + (size_t)i * 4096;
    #pragma unroll
    for (int ot = 0; ot < 4; ++ot){
      f32x4 acc = {0.f,0.f,0.f,0.f};
      #pragma unroll
      for (int c = 0; c < 2; ++c){
        bf16x8 bfr = *(const bf16x8*)(Wb + (size_t)(lo + 16*ot) * 64 + 32*c + 8*hi);
        acc = __builtin_amdgcn_mfma_f32_16x16x32_bf16(afr[c], bfr, acc, 0, 0, 0);
      }
      #pragma unroll
      for (int r = 0; r < 4; ++r)
        Cl[(w*16 + hi*4 + r)*72 + lo + 16*ot] = (short)f2bf(acc[r]);
    }
    __syncthreads();
    #pragma unroll
    for (int cc = 0; cc < 2; ++cc){
      int c2 = threadIdx.x + cc*256;
      int mm = c2 & 7, hh = (c2>>3)&7, sblk = c2>>6;
      int a5 = sblk>>2, slot = sblk&3;
      short tmp[8];
      #pragma unroll
      for (int jj = 0; jj < 8; ++jj){
        int s_j = a5*32 + (jj>>2)*16 + slot*4 + (jj&3);
        tmp[jj] = Cl[s_j*72 + hh*8 + mm];
      }
      int fh = rr>>1, fl = (rr&1)*8 + mm;
      size_t a = (size_t)((b8 + hh)*32 + tile64*2 + a5)*6144 + 3072
               + (size_t)(fh*64 + slot*16 + fl)*8;
      *(bf16x8*)(KVg + a) = *(const bf16x8*)tmp;
    }
  }
}

// ---------------- Kernel B: flash attention (counted-vmcnt pipeline) ----------------
// grid 512: bh = (bid&7)*8 + ((bid>>3)&7), qt = bid>>6 (0..7, q-tile 128).
// 4 waves x 32 q (g=2). 32 KV tiles of 32; 3 LDS buffers, stage-ahead 2.
// Per tile: vmcnt(3) [own tile-t loads done, t+1 in flight] -> raw s_barrier
// [all waves' tile-t loads done] -> STAGE(t+2) -> compute(t). No full drain.
__global__ __launch_bounds__(256, 4) void attn(
    const ushort_t* __restrict__ Qg,
    const ushort_t* __restrict__ KVg,
    ushort_t* __restrict__ Oc)
{
  __shared__ __align__(16) short KVl[3][6144];   // [buf][K 3072 | V 3072]

  const int bid = blockIdx.x;
  const int bh = (bid & 7)*8 + ((bid >> 3) & 7);
  const int qt = bid >> 6;                      // 0..7
  const int tid = threadIdx.x;
  const int w = tid >> 6, lane = tid & 63;
  const int lo = lane & 15, hi = lane >> 4;
  const size_t qbase  = (size_t)bh * 16 * 6144;
  const size_t kvbase = (size_t)bh * 32 * 6144;

  // Q fragments (B-operand), frag-order lane-linear loads
  bf16x8 qf[2][3];
  #pragma unroll
  for (int g = 0; g < 2; ++g){
    int qq = qt*128 + w*32 + g*16;
    const ushort_t* qb = Qg + qbase + (size_t)(qq >> 6)*6144 + (size_t)(((qq>>4)&3)*3)*512;
    #pragma unroll
    for (int c = 0; c < 3; ++c)
      qf[g][c] = *(const bf16x8*)(qb + (c*64 + lane)*8);
  }

  f32x4 acc[6][2];
  #pragma unroll
  for (int ft = 0; ft < 6; ++ft){ acc[ft][0] = (f32x4){0,0,0,0}; acc[ft][1] = (f32x4){0,0,0,0}; }
  float lr[2] = {0.f, 0.f};

#define STAGE(tt, bb) do { \
    const ushort_t* kv_ = KVg + kvbase + (size_t)(tt)*6144 + tid*8; \
    short* l_ = &KVl[bb][tid*8]; \
    gll16(kv_, l_); gll16(kv_ + 2048, l_ + 2048); gll16(kv_ + 4096, l_ + 4096); \
  } while(0)

  STAGE(0, 0);
  STAGE(1, 1);

  int cb = 0;                       // compute buffer for tile t
  for (int t = 0; t < 32; ++t){
    if (t < 31) asm volatile("s_waitcnt vmcnt(3)" ::: "memory");
    else        asm volatile("s_waitcnt vmcnt(0)" ::: "memory");
    __builtin_amdgcn_s_barrier();
    if (t < 30){
      int sb = cb + 2; if (sb >= 3) sb -= 3;
      STAGE(t+2, sb);
    }
    const short* kb = &KVl[cb][0];

    // QK^T (swapped): st[g][kvb][r] = S^T[kv=16kvb+4hi+r][q]
    f32x4 st[2][2];
    __builtin_amdgcn_s_setprio(1);
    #pragma unroll
    for (int kvb = 0; kvb < 2; ++kvb){
      bf16x8 kf[3];
      #pragma unroll
      for (int c = 0; c < 3; ++c)
        kf[c] = *(const bf16x8*)&kb[((kvb*3 + c)*64 + lane)*8];
      #pragma unroll
      for (int g = 0; g < 2; ++g){
        f32x4 s = {0.f,0.f,0.f,0.f};
        #pragma unroll
        for (int c = 0; c < 3; ++c)
          s = __builtin_amdgcn_mfma_f32_16x16x32_bf16(kf[c], qf[g][c], s, 0, 0, 0);
        st[g][kvb] = s;
      }
    }
    __builtin_amdgcn_s_setprio(0);

    // no-max softmax: p = exp2(s); lane-partial denominator; pack own regs
    bf16x8 pb[2];
    #pragma unroll
    for (int g = 0; g < 2; ++g){
      #pragma unroll
      for (int kvb = 0; kvb < 2; ++kvb)
        #pragma unroll
        for (int r = 0; r < 4; ++r){ st[g][kvb][r] = exp2x(st[g][kvb][r]); lr[g] += st[g][kvb][r]; }
      union { uint32_t u[4]; bf16x8 v; } pu;
      pu.u[0] = pk2bf(st[g][0][0], st[g][0][1]);
      pu.u[1] = pk2bf(st[g][0][2], st[g][0][3]);
      pu.u[2] = pk2bf(st[g][1][0], st[g][1][1]);
      pu.u[3] = pk2bf(st[g][1][2], st[g][1][3]);
      pb[g] = pu.v;
    }

    // PV: O^T[f][q] += V^T-frag (pi-order) x P-frag (own regs)
    __builtin_amdgcn_s_setprio(1);
    #pragma unroll
    for (int ft = 0; ft < 6; ++ft){
      bf16x8 va = *(const bf16x8*)&kb[3072 + (ft*64 + lane)*8];
      acc[ft][0] = __builtin_amdgcn_mfma_f32_16x16x32_bf16(va, pb[0], acc[ft][0], 0, 0, 0);
      acc[ft][1] = __builtin_amdgcn_mfma_f32_16x16x32_bf16(va, pb[1], acc[ft][1], 0, 0, 0);
    }
    __builtin_amdgcn_s_setprio(0);

    cb = (cb == 2) ? 0 : cb + 1;
  }
#undef STAGE

  // epilogue: reduce l across lane groups; Oc frag layout
  #pragma unroll
  for (int g = 0; g < 2; ++g){
    float l = lr[g];
    l += __shfl_xor(l, 16);
    l += __shfl_xor(l, 32);
    float rl = 1.f / l;
    int q = qt*128 + w*32 + g*16 + lo;
    #pragma unroll
    for (int ft = 0; ft < 6; ++ft){
      uint2 o;
      o.x = pk2bf(acc[ft][g][0]*rl, acc[ft][g][1]*rl);
      o.y = pk2bf(acc[ft][g][2]*rl, acc[ft][g][3]*rl);
      size_t ad = ((size_t)(bh*24 + ft*4 + hi)*1024 + q)*4;
      *(uint2*)(Oc + ad) = o;
    }
  }
}

// ---------------- Kernel C: output projection ----------------
__global__ __launch_bounds__(256) void out_proj(
    const ushort_t* __restrict__ Oc,
    const ushort_t* __restrict__ Wb4,
    float* __restrict__ out)
{
  const int tile = blockIdx.x;
  const int rr = tile >> 7, rt = tile & 127;
  int i, dx, d; rr_decode(rr, i, dx, d); (void)dx; (void)d;

  const int lane = threadIdx.x & 63;
  const int w    = threadIdx.x >> 6;
  const int lo = lane & 15, hi = lane >> 4;

  bf16x8 afr[2];
  {
    const int R = rt*64 + w*16 + lo;
    const int b = R >> 10, s = R & 1023;
    union { uint2 u2[2]; bf16x8 v; } a0, a1;
    #pragma unroll
    for (int jj = 0; jj < 2; ++jj){
      a0.u2[jj] = *(const uint2*)(Oc + ((size_t)((b*8 + hi)*24 + 2*rr + jj)*1024 + s)*4);
      a1.u2[jj] = *(const uint2*)(Oc + ((size_t)((b*8 + 4 + hi)*24 + 2*rr + jj)*1024 + s)*4);
    }
    afr[0] = a0.v;
    afr[1] = a1.v;
  }

  const ushort_t* Wb = Wb4 + (size_t)3*28672 + (size_t)i * 4096;
  #pragma unroll
  for (int ot = 0; ot < 4; ++ot){
    f32x4 acc = {0.f,0.f,0.f,0.f};
    #pragma unroll
    for (int c = 0; c < 2; ++c){
      bf16x8 bfr = *(const bf16x8*)(Wb + (size_t)(lo + 16*ot) * 64 + 32*c + 8*hi);
      acc = __builtin_amdgcn_mfma_f32_16x16x32_bf16(afr[c], bfr, acc, 0, 0, 0);
    }
    #pragma unroll
    for (int r = 0; r < 4; ++r){
      int bs = rt*64 + w*16 + hi*4 + r;
      out[(size_t)(bs*12 + rr)*64 + lo + 16*ot] = acc[r];
    }
  }
}

extern "C" void kernel_launch(void* const* d_in, const int* in_sizes, int n_in,
                              void* d_out, int out_size, void* d_ws, size_t ws_size,
                              hipStream_t stream)
{
  const float* xA1 = (const float*)d_in[0];
  const float* xB2 = (const float*)d_in[1];
  const float* xE1 = (const float*)d_in[2];
  const float* xE2 = (const float*)d_in[3];
  const float* xE3 = (const float*)d_in[4];
  const float* xE4 = (const float*)d_in[5];
  const float* xE5 = (const float*)d_in[6];
  const float* Wq  = (const float*)d_in[7];
  const float* Wk  = (const float*)d_in[8];
  const float* Wv  = (const float*)d_in[9];
  const float* Wo  = (const float*)d_in[10];

  ushort_t* Qg  = (ushort_t*)d_ws;
  ushort_t* KVg = Qg + NE;                  // 2*NE (K+V interleaved, 32-kv groups)
  ushort_t* Oc  = KVg + (size_t)2*NE;
  ushort_t* Wb4 = Oc + NE;                  // 4*28672 bf16

  wconv<<<dim3(14,4), dim3(256), 0, stream>>>(Wq, Wk, Wv, Wo, Wb4);
  qkv_proj<<<dim3(1536), dim3(256), 0, stream>>>(xA1,xB2,xE1,xE2,xE3,xE4,xE5,
                                                 Wb4, Qg, KVg);
  attn<<<dim3(512), dim3(256), 0, stream>>>(Qg, KVg, Oc);
  out_proj<<<dim3(1536), dim3(256), 0, stream>>>(Oc, Wb4, (float*)d_out);
}

// Round 10
// 71.602 us; speedup vs baseline: 1.0030x; 1.0030x over previous
//
#include <hip/hip_runtime.h>
#include <stdint.h>

typedef __attribute__((ext_vector_type(8))) short bf16x8;
typedef __attribute__((ext_vector_type(4))) float f32x4;
typedef unsigned short ushort_t;

#define NE 6291456   // 8*1024*12*64 elements

__device__ __forceinline__ unsigned short f2bf(float f){
  union { float f; unsigned u; } c; c.f = f;
  unsigned u = c.u;
  u = u + 0x7FFFu + ((u >> 16) & 1u);
  return (unsigned short)(u >> 16);
}

__device__ __forceinline__ bf16x8 cvt8(const float* p){
  const float4 a = ((const float4*)p)[0];
  const float4 b = ((const float4*)p)[1];
  bf16x8 r;
  r[0]=(short)f2bf(a.x); r[1]=(short)f2bf(a.y); r[2]=(short)f2bf(a.z); r[3]=(short)f2bf(a.w);
  r[4]=(short)f2bf(b.x); r[5]=(short)f2bf(b.y); r[6]=(short)f2bf(b.z); r[7]=(short)f2bf(b.w);
  return r;
}

__device__ __forceinline__ uint32_t pk2bf(float a, float b){
  uint32_t r;
  asm("v_cvt_pk_bf16_f32 %0, %1, %2" : "=v"(r) : "v"(a), "v"(b));
  return r;
}

__device__ __forceinline__ float exp2x(float x){
  float r;
  asm("v_exp_f32 %0, %1" : "=v"(r) : "v"(x));
  return r;
}

__device__ __forceinline__ void gll16(const ushort_t* g, short* l){
  __builtin_amdgcn_global_load_lds(
      (const __attribute__((address_space(1))) unsigned int*)g,
      (__attribute__((address_space(3))) unsigned int*)l, 16, 0, 0);
}

// rr (0..11) -> key index, dx, d
__device__ __forceinline__ void rr_decode(int rr, int& i, int& dx, int& d){
  if (rr < 2){ i = rr; dx = 0; d = 1; }
  else { i = 2 + ((rr-2)>>1); dx = (rr-2)&1; d = 2; }
}

// ---------------- Kernel 0: weight pre-convert f32 -> bf16 ----------------
__global__ __launch_bounds__(256) void wconv(
    const float* __restrict__ Wq, const float* __restrict__ Wk,
    const float* __restrict__ Wv, const float* __restrict__ Wo,
    ushort_t* __restrict__ out)
{
  const int a = blockIdx.y;
  const float* src = (a==0)?Wq:(a==1)?Wk:(a==2)?Wv:Wo;
  const float sc = (a==0) ? 0.14724743479535623f : 1.0f;  // log2(e)/sqrt(96)
  const int i = (blockIdx.x*256 + threadIdx.x)*8;
  float4 v0 = *(const float4*)(src+i);
  float4 v1 = *(const float4*)(src+i+4);
  uint4 o;
  o.x = pk2bf(v0.x*sc, v0.y*sc);
  o.y = pk2bf(v0.z*sc, v0.w*sc);
  o.z = pk2bf(v1.x*sc, v1.y*sc);
  o.w = pk2bf(v1.z*sc, v1.w*sc);
  *(uint4*)(out + (size_t)a*28672 + i) = o;
}

// ---------------- Kernel A: QKV projection ----------------
// Block = (rr, 64 bs-rows). Q: register-direct C^T stores to Qg (64-s tiles).
// K,V: combined KVg buffer, 32-kv groups of 6144 shorts: [K 3072][V 3072].
__global__ __launch_bounds__(256) void qkv_proj(
    const float* __restrict__ xA1, const float* __restrict__ xB2,
    const float* __restrict__ xE1, const float* __restrict__ xE2,
    const float* __restrict__ xE3, const float* __restrict__ xE4,
    const float* __restrict__ xE5,
    const ushort_t* __restrict__ Wb4,
    ushort_t* __restrict__ Qg, ushort_t* __restrict__ KVg)
{
  __shared__ short Cl[64*72];            // V out tile [64 s][64 o], stride 72

  const int tile = blockIdx.x;           // 0..1535
  const int rr = tile >> 7, rt = tile & 127;
  int i, dx, d; rr_decode(rr, i, dx, d);
  const float* xp = (i==0)?xA1:(i==1)?xB2:(i==2)?xE1:(i==3)?xE2:(i==4)?xE3:(i==5)?xE4:xE5;

  const int lane = threadIdx.x & 63;
  const int w    = threadIdx.x >> 6;
  const int lo = lane & 15, hi = lane >> 4;
  const int b8 = (rt >> 4) * 8;
  const int tile64 = rt & 15;

  bf16x8 afr[2];
  {
    const int R = rt*64 + w*16 + lo;
    const float* rp = xp + (size_t)(R*d + dx) * 64;
    afr[0] = cvt8(rp + 8*hi);
    afr[1] = cvt8(rp + 32 + 8*hi);
  }

  // ---- Q: C^T form, register-direct stores (64-s tile layout) ----
  {
    const ushort_t* Wb = Wb4 + (size_t)i * 4096;
    #pragma unroll
    for (int ot = 0; ot < 4; ++ot){
      f32x4 acc = {0.f,0.f,0.f,0.f};
      #pragma unroll
      for (int c = 0; c < 2; ++c){
        bf16x8 bfr = *(const bf16x8*)(Wb + (size_t)(lo + 16*ot) * 64 + 32*c + 8*hi);
        acc = __builtin_amdgcn_mfma_f32_16x16x32_bf16(bfr, afr[c], acc, 0, 0, 0);
      }
      uint2 o2;
      o2.x = pk2bf(acc[0], acc[1]);
      o2.y = pk2bf(acc[2], acc[3]);
      int hh = 2*ot + (hi>>1);
      size_t a = (size_t)((b8 + hh)*16 + tile64)*6144
               + (size_t)((w*3 + (rr>>2))*64 + (rr&3)*16 + lo)*8 + 4*(hi&1);
      *(uint2*)(Qg + a) = o2;
    }
  }

  // ---- K: C^T form, register-direct stores (32-kv combined layout) ----
  {
    const ushort_t* Wb = Wb4 + (size_t)28672 + (size_t)i * 4096;
    #pragma unroll
    for (int ot = 0; ot < 4; ++ot){
      f32x4 acc = {0.f,0.f,0.f,0.f};
      #pragma unroll
      for (int c = 0; c < 2; ++c){
        bf16x8 bfr = *(const bf16x8*)(Wb + (size_t)(lo + 16*ot) * 64 + 32*c + 8*hi);
        acc = __builtin_amdgcn_mfma_f32_16x16x32_bf16(bfr, afr[c], acc, 0, 0, 0);
      }
      uint2 o2;
      o2.x = pk2bf(acc[0], acc[1]);
      o2.y = pk2bf(acc[2], acc[3]);
      int hh = 2*ot + (hi>>1);
      size_t a = (size_t)((b8 + hh)*32 + tile64*2 + (w>>1))*6144
               + (size_t)(((w&1)*3 + (rr>>2))*64 + (rr&3)*16 + lo)*8 + 4*(hi&1);
      *(uint2*)(KVg + a) = o2;
    }
  }

  // ---- V: via LDS permute path (pi-permuted kv slots) ----
  {
    const ushort_t* Wb = Wb4 + (size_t)2*28672 + (size_t)i * 4096;
    #pragma unroll
    for (int ot = 0; ot < 4; ++ot){
      f32x4 acc = {0.f,0.f,0.f,0.f};
      #pragma unroll
      for (int c = 0; c < 2; ++c){
        bf16x8 bfr = *(const bf16x8*)(Wb + (size_t)(lo + 16*ot) * 64 + 32*c + 8*hi);
        acc = __builtin_amdgcn_mfma_f32_16x16x32_bf16(afr[c], bfr, acc, 0, 0, 0);
      }
      #pragma unroll
      for (int r = 0; r < 4; ++r)
        Cl[(w*16 + hi*4 + r)*72 + lo + 16*ot] = (short)f2bf(acc[r]);
    }
    __syncthreads();
    #pragma unroll
    for (int cc = 0; cc < 2; ++cc){
      int c2 = threadIdx.x + cc*256;
      int mm = c2 & 7, hh = (c2>>3)&7, sblk = c2>>6;
      int a5 = sblk>>2, slot = sblk&3;
      short tmp[8];
      #pragma unroll
      for (int jj = 0; jj < 8; ++jj){
        int s_j = a5*32 + (jj>>2)*16 + slot*4 + (jj&3);
        tmp[jj] = Cl[s_j*72 + hh*8 + mm];
      }
      int fh = rr>>1, fl = (rr&1)*8 + mm;
      size_t a = (size_t)((b8 + hh)*32 + tile64*2 + a5)*6144 + 3072
               + (size_t)(fh*64 + slot*16 + fl)*8;
      *(bf16x8*)(KVg + a) = *(const bf16x8*)tmp;
    }
  }
}

// ---------------- Kernel B: flash attention (wq x wk wave split) ----------------
// grid 512: bh = (bid&7)*8 + ((bid>>3)&7), qt = bid>>6 (0..7, q-tile 128).
// Wave w: wq=w&1 owns q-half (64 q, g=4), wk=w>>1 owns kv stream (tiles 2j+wk).
// Each K/V b128 read feeds 4 MFMA; each tile read by 2 waves (was 4): LDS reads
// halved vs r8. No-max softmax => partial acc/l merge across wk is a pure sum.
__global__ __launch_bounds__(256, 2) void attn(
    const ushort_t* __restrict__ Qg,
    const ushort_t* __restrict__ KVg,
    ushort_t* __restrict__ Oc)
{
  __shared__ __align__(16) short KVl[2][2][6144];   // [stream][buf][K 3072 | V 3072]
  __shared__ float Lx[2][4][64];                     // l exchange [wq][g][lane]

  const int bid = blockIdx.x;
  const int bh = (bid & 7)*8 + ((bid >> 3) & 7);
  const int qt = bid >> 6;                      // 0..7
  const int tid = threadIdx.x;
  const int w = tid >> 6, lane = tid & 63;
  const int wq = w & 1, wk = w >> 1;
  const int lo = lane & 15, hi = lane >> 4;
  const size_t qbase  = (size_t)bh * 16 * 6144;
  const size_t kvbase = (size_t)bh * 32 * 6144;

  // Q fragments (B-operand): 4 g-groups of 16 q (q = qt*128 + wq*64 + g*16)
  bf16x8 qf[4][3];
  {
    const ushort_t* qb = Qg + qbase + (size_t)(2*qt + wq)*6144;
    #pragma unroll
    for (int g = 0; g < 4; ++g)
      #pragma unroll
      for (int c = 0; c < 3; ++c)
        qf[g][c] = *(const bf16x8*)(qb + ((g*3 + c)*64 + lane)*8);
  }

  f32x4 acc[6][4];
  #pragma unroll
  for (int ft = 0; ft < 6; ++ft)
    #pragma unroll
    for (int g = 0; g < 4; ++g) acc[ft][g] = (f32x4){0,0,0,0};
  float lr[4] = {0.f, 0.f, 0.f, 0.f};

#define STAGE(jj, bb) do { \
    const ushort_t* kv_ = KVg + kvbase + (size_t)(2*(jj)+wk)*6144 + wq*3072 + lane*8; \
    short* l_ = &KVl[wk][bb][wq*3072 + lane*8]; \
    gll16(kv_,        l_);        gll16(kv_ + 512,  l_ + 512); \
    gll16(kv_ + 1024, l_ + 1024); gll16(kv_ + 1536, l_ + 1536); \
    gll16(kv_ + 2048, l_ + 2048); gll16(kv_ + 2560, l_ + 2560); \
  } while(0)

  STAGE(0, 0);
  __syncthreads();

  for (int j = 0; j < 16; ++j){
    if (j < 15) STAGE(j+1, (j+1)&1);
    const short* kb = &KVl[wk][j&1][0];

    // QK^T (swapped): st[g][kvb][r] = S^T[kv=16kvb+4hi+r][q]
    f32x4 st[4][2];
    __builtin_amdgcn_s_setprio(1);
    #pragma unroll
    for (int kvb = 0; kvb < 2; ++kvb){
      bf16x8 kf[3];
      #pragma unroll
      for (int c = 0; c < 3; ++c)
        kf[c] = *(const bf16x8*)&kb[((kvb*3 + c)*64 + lane)*8];
      #pragma unroll
      for (int g = 0; g < 4; ++g){
        f32x4 s = {0.f,0.f,0.f,0.f};
        #pragma unroll
        for (int c = 0; c < 3; ++c)
          s = __builtin_amdgcn_mfma_f32_16x16x32_bf16(kf[c], qf[g][c], s, 0, 0, 0);
        st[g][kvb] = s;
      }
    }
    __builtin_amdgcn_s_setprio(0);

    // no-max softmax: p = exp2(s); lane-partial denominator; pack own regs
    bf16x8 pb[4];
    #pragma unroll
    for (int g = 0; g < 4; ++g){
      #pragma unroll
      for (int kvb = 0; kvb < 2; ++kvb)
        #pragma unroll
        for (int r = 0; r < 4; ++r){ st[g][kvb][r] = exp2x(st[g][kvb][r]); lr[g] += st[g][kvb][r]; }
      union { uint32_t u[4]; bf16x8 v; } pu;
      pu.u[0] = pk2bf(st[g][0][0], st[g][0][1]);
      pu.u[1] = pk2bf(st[g][0][2], st[g][0][3]);
      pu.u[2] = pk2bf(st[g][1][0], st[g][1][1]);
      pu.u[3] = pk2bf(st[g][1][2], st[g][1][3]);
      pb[g] = pu.v;
    }

    // PV: O^T[f][q] += V^T-frag (pi-order) x P-frag (own regs)
    __builtin_amdgcn_s_setprio(1);
    #pragma unroll
    for (int ft = 0; ft < 6; ++ft){
      bf16x8 va = *(const bf16x8*)&kb[3072 + (ft*64 + lane)*8];
      #pragma unroll
      for (int g = 0; g < 4; ++g)
        acc[ft][g] = __builtin_amdgcn_mfma_f32_16x16x32_bf16(va, pb[g], acc[ft][g], 0, 0, 0);
    }
    __builtin_amdgcn_s_setprio(0);

    __syncthreads();
  }
#undef STAGE

  // ---- merge across wk (partials are pure sums; no-max softmax) ----
  // reduce l over hi-groups within each wave first
  #pragma unroll
  for (int g = 0; g < 4; ++g){
    lr[g] += __shfl_xor(lr[g], 16);
    lr[g] += __shfl_xor(lr[g], 32);
  }

  float* facc = (float*)&KVl[0][0][0];   // 48 KB: [wq][ft][g][lane] f32x4
  if (wk == 1){
    #pragma unroll
    for (int ft = 0; ft < 6; ++ft)
      #pragma unroll
      for (int g = 0; g < 4; ++g)
        *(f32x4*)&facc[(((wq*6 + ft)*4 + g)*64 + lane)*4] = acc[ft][g];
    #pragma unroll
    for (int g = 0; g < 4; ++g) Lx[wq][g][lane] = lr[g];
  }
  __syncthreads();
  if (wk == 0){
    float rl[4];
    #pragma unroll
    for (int g = 0; g < 4; ++g) rl[g] = 1.f / (lr[g] + Lx[wq][g][lane]);
    #pragma unroll
    for (int ft = 0; ft < 6; ++ft){
      #pragma unroll
      for (int g = 0; g < 4; ++g){
        f32x4 o = acc[ft][g] + *(const f32x4*)&facc[(((wq*6 + ft)*4 + g)*64 + lane)*4];
        uint2 ou;
        ou.x = pk2bf(o[0]*rl[g], o[1]*rl[g]);
        ou.y = pk2bf(o[2]*rl[g], o[3]*rl[g]);
        int q = qt*128 + wq*64 + g*16 + lo;
        size_t ad = ((size_t)(bh*24 + ft*4 + hi)*1024 + q)*4;
        *(uint2*)(Oc + ad) = ou;
      }
    }
  }
}

// ---------------- Kernel C: output projection ----------------
__global__ __launch_bounds__(256) void out_proj(
    const ushort_t* __restrict__ Oc,
    const ushort_t* __restrict__ Wb4,
    float* __restrict__ out)
{
  const int tile = blockIdx.x;
  const int rr = tile >> 7, rt = tile & 127;
  int i, dx, d; rr_decode(rr, i, dx, d); (void)dx; (void)d;

  const int lane = threadIdx.x & 63;
  const int w    = threadIdx.x >> 6;
  const int lo = lane & 15, hi = lane >> 4;

  bf16x8 afr[2];
  {
    const int R = rt*64 + w*16 + lo;
    const int b = R >> 10, s = R & 1023;
    union { uint2 u2[2]; bf16x8 v; } a0, a1;
    #pragma unroll
    for (int jj = 0; jj < 2; ++jj){
      a0.u2[jj] = *(const uint2*)(Oc + ((size_t)((b*8 + hi)*24 + 2*rr + jj)*1024 + s)*4);
      a1.u2[jj] = *(const uint2*)(Oc + ((size_t)((b*8 + 4 + hi)*24 + 2*rr + jj)*1024 + s)*4);
    }
    afr[0] = a0.v;
    afr[1] = a1.v;
  }

  const ushort_t* Wb = Wb4 + (size_t)3*28672 + (size_t)i * 4096;
  #pragma unroll
  for (int ot = 0; ot < 4; ++ot){
    f32x4 acc = {0.f,0.f,0.f,0.f};
    #pragma unroll
    for (int c = 0; c < 2; ++c){
      bf16x8 bfr = *(const bf16x8*)(Wb + (size_t)(lo + 16*ot) * 64 + 32*c + 8*hi);
      acc = __builtin_amdgcn_mfma_f32_16x16x32_bf16(afr[c], bfr, acc, 0, 0, 0);
    }
    #pragma unroll
    for (int r = 0; r < 4; ++r){
      int bs = rt*64 + w*16 + hi*4 + r;
      out[(size_t)(bs*12 + rr)*64 + lo + 16*ot] = acc[r];
    }
  }
}

extern "C" void kernel_launch(void* const* d_in, const int* in_sizes, int n_in,
                              void* d_out, int out_size, void* d_ws, size_t ws_size,
                              hipStream_t stream)
{
  const float* xA1 = (const float*)d_in[0];
  const float* xB2 = (const float*)d_in[1];
  const float* xE1 = (const float*)d_in[2];
  const float* xE2 = (const float*)d_in[3];
  const float* xE3 = (const float*)d_in[4];
  const float* xE4 = (const float*)d_in[5];
  const float* xE5 = (const float*)d_in[6];
  const float* Wq  = (const float*)d_in[7];
  const float* Wk  = (const float*)d_in[8];
  const float* Wv  = (const float*)d_in[9];
  const float* Wo  = (const float*)d_in[10];

  ushort_t* Qg  = (ushort_t*)d_ws;
  ushort_t* KVg = Qg + NE;                  // 2*NE (K+V interleaved, 32-kv groups)
  ushort_t* Oc  = KVg + (size_t)2*NE;
  ushort_t* Wb4 = Oc + NE;                  // 4*28672 bf16

  wconv<<<dim3(14,4), dim3(256), 0, stream>>>(Wq, Wk, Wv, Wo, Wb4);
  qkv_proj<<<dim3(1536), dim3(256), 0, stream>>>(xA1,xB2,xE1,xE2,xE3,xE4,xE5,
                                                 Wb4, Qg, KVg);
  attn<<<dim3(512), dim3(256), 0, stream>>>(Qg, KVg, Oc);
  out_proj<<<dim3(1536), dim3(256), 0, stream>>>(Oc, Wb4, (float*)d_out);
}